// Round 3
// baseline (4224.485 us; speedup 1.0000x reference)
//
#include <hip/hip_runtime.h>
#include <math.h>

// DecoderCenter — Round 3: bf16-MFMA GEMM chain (fp32 activations, bf16 weights/LDS),
// fp32 conv stack / PE / base1 / head unchanged.

#define LRELU(v) ((v) >= 0.0f ? (v) : 0.01f * (v))

static constexpr int BATCH = 4;
static constexpr int NPTS  = 8192;
static constexpr int ROWS  = BATCH * NPTS;   // 32768

typedef short bf16x8 __attribute__((ext_vector_type(8)));
typedef float f32x4  __attribute__((ext_vector_type(4)));

// fp32 -> bf16 (RNE)
static __device__ __forceinline__ short f2bf(float f) {
    unsigned u = __float_as_uint(f);
    unsigned r = (u + 0x7fffu + ((u >> 16) & 1u)) >> 16;
    return (short)r;
}

// ---------------- grouped 3x3 conv + bias + leaky ----------------
__global__ void conv3x3_kernel(const float* __restrict__ in, const float* __restrict__ wt,
                               const float* __restrict__ bias, float* __restrict__ out,
                               int Bn, int Cin, int Cout, int H, int W, int pad, int G) {
    int Ho = H + 2 * pad - 2, Wo = W + 2 * pad - 2;
    int total = Bn * Cout * Ho * Wo;
    int idx = blockIdx.x * blockDim.x + threadIdx.x;
    if (idx >= total) return;
    int ow = idx % Wo; int t = idx / Wo;
    int oh = t % Ho; t /= Ho;
    int oc = t % Cout; int b = t / Cout;
    int CinG = Cin / G;
    int OG = Cout / G;
    int g = oc / OG;
    const float* inb = in + ((long)b * Cin + (long)g * CinG) * H * W;
    const float* wr = wt + (long)oc * CinG * 9;
    float acc = bias[oc];
    for (int ic = 0; ic < CinG; ++ic) {
        const float* ip = inb + ic * H * W;
        const float* wp = wr + ic * 9;
        #pragma unroll
        for (int kh = 0; kh < 3; ++kh) {
            int ih = oh + kh - pad;
            if (ih < 0 || ih >= H) continue;
            #pragma unroll
            for (int kw = 0; kw < 3; ++kw) {
                int iw = ow + kw - pad;
                if (iw < 0 || iw >= W) continue;
                acc += ip[ih * W + iw] * wp[kh * 3 + kw];
            }
        }
    }
    out[idx] = LRELU(acc);
}

// ---------------- positional encoding ----------------
__global__ void pe_kernel(const float* __restrict__ points, float* __restrict__ pe, int total) {
    int idx = blockIdx.x * blockDim.x + threadIdx.x;
    if (idx >= total) return;
    int j = idx & 31;
    int r = idx >> 5;
    int oct = j >> 1, c = j & 1;
    float f = exp2f(0.5f * (float)oct);
    pe[idx] = sinf(points[r * 2 + c] * f);
}

// ---------------- base1[b,o] = lin1_b[o] + feat[b,:] @ lin1_W[o, 32:2080] ----------------
__global__ void base1_kernel(const float* __restrict__ feat, const float* __restrict__ W,
                             const float* __restrict__ b, float* __restrict__ base) {
    int wid = (int)((blockIdx.x * blockDim.x + threadIdx.x) >> 6);
    int lane = threadIdx.x & 63;
    if (wid >= BATCH * 1024) return;
    int bb = wid >> 10, oc = wid & 1023;
    const float* fr = feat + bb * 2048;
    const float* wr = W + (long)oc * 2080 + 32;
    float acc = 0.f;
    for (int k = lane; k < 2048; k += 64) acc += fr[k] * wr[k];
    #pragma unroll
    for (int off = 32; off; off >>= 1) acc += __shfl_down(acc, off);
    if (lane == 0) base[wid] = acc + b[oc];
}

// ---------------- weight conversion fp32 -> bf16 ----------------
__global__ void cvt_bf16_kernel(const float* __restrict__ in, short* __restrict__ out, int n4) {
    int i = blockIdx.x * blockDim.x + threadIdx.x;   // one float4 per thread
    if (i >= n4) return;
    float4 v = *(const float4*)(in + (size_t)i * 4);
    short4 s;
    s.x = f2bf(v.x); s.y = f2bf(v.y); s.z = f2bf(v.z); s.w = f2bf(v.w);
    *(short4*)(out + (size_t)i * 4) = s;
}

// extract lin1_W[:, 0:32] -> bf16 [1024][32]
__global__ void cvt_w1pe_kernel(const float* __restrict__ W, short* __restrict__ out) {
    int i = blockIdx.x * blockDim.x + threadIdx.x;   // 1024*32
    if (i >= 1024 * 32) return;
    int r = i >> 5, c = i & 31;
    out[i] = f2bf(W[(size_t)r * 2080 + c]);
}

// ---------------- bf16-MFMA GEMM, fused epilogue ----------------
// C[r,c] = ep( sum_k A1[r,k] W[c,k] (k<K1) + sum_k A2[r,k] W[c,K1+k] (k<K2) )
// A* fp32 (converted to bf16 during LDS staging), W bf16 row-major [N][K1+K2].
// BM=128, BN=64, BK=32. 256 threads = 4 waves (2x2), each wave 64x32 out.
// LDS fragment-ordered: elem (row,k) at ((row>>4)*4 + (k>>3))*128 + (row&15)*8 + (k&7)
template<int BIAS_MODE, bool LEAKY, bool RESID>
__global__ __launch_bounds__(256) void mgemm(
    const float* __restrict__ A1, int lda1, int K1,
    const float* __restrict__ A2, int lda2, int K2,
    const short* __restrict__ W, int ldw,
    const float* __restrict__ bias, int ldbias,
    float* __restrict__ C, int ldc,
    const float* __restrict__ resid, int ldres)
{
    __shared__ short Al[128 * 32];   // 8 KB
    __shared__ short Bl[64 * 32];    // 4 KB
    const int r0 = blockIdx.y * 128, c0 = blockIdx.x * 64;
    const int tid = threadIdx.x;
    const int lane = tid & 63, w = tid >> 6;
    const int wr = (w >> 1) * 64, wc = (w & 1) * 32;    // wave tile origin
    const int l16 = lane & 15, lg = lane >> 4;

    f32x4 acc[4][2] = {};

    // staging maps
    const int sar = tid >> 1, sak = (tid & 1) * 16;     // A: row, k-quarter (16 floats)
    const int sbc = tid >> 2, sbk = tid & 3;            // B: col, k-group (8 bf16)

    for (int src = 0; src < 2; ++src) {
        const float* A = src ? A2 : A1;
        const int K   = src ? K2 : K1;
        const int lda = src ? lda2 : lda1;
        const int kb  = src ? K1 : 0;
        if (K == 0) continue;
        for (int kt = 0; kt < K; kt += 32) {
            __syncthreads();
            // --- stage A: 16 fp32 -> 16 bf16 per thread, 2x ds_write_b128 ---
            {
                const float* ap = A + (size_t)(r0 + sar) * lda + kt + sak;
                float4 v0 = *(const float4*)(ap + 0);
                float4 v1 = *(const float4*)(ap + 4);
                float4 v2 = *(const float4*)(ap + 8);
                float4 v3 = *(const float4*)(ap + 12);
                bf16x8 s0, s1;
                s0[0] = f2bf(v0.x); s0[1] = f2bf(v0.y); s0[2] = f2bf(v0.z); s0[3] = f2bf(v0.w);
                s0[4] = f2bf(v1.x); s0[5] = f2bf(v1.y); s0[6] = f2bf(v1.z); s0[7] = f2bf(v1.w);
                s1[0] = f2bf(v2.x); s1[1] = f2bf(v2.y); s1[2] = f2bf(v2.z); s1[3] = f2bf(v2.w);
                s1[4] = f2bf(v3.x); s1[5] = f2bf(v3.y); s1[6] = f2bf(v3.z); s1[7] = f2bf(v3.w);
                int base = ((sar >> 4) * 4 + (sak >> 3)) * 128 + (sar & 15) * 8;
                *(bf16x8*)&Al[base]       = s0;
                *(bf16x8*)&Al[base + 128] = s1;
            }
            // --- stage B: 8 bf16 per thread (weights already bf16) ---
            {
                const short* bp = W + (size_t)(c0 + sbc) * ldw + kb + kt + sbk * 8;
                bf16x8 bv = *(const bf16x8*)bp;
                *(bf16x8*)&Bl[((sbc >> 4) * 4 + sbk) * 128 + (sbc & 15) * 8] = bv;
            }
            __syncthreads();
            // --- fragments + MFMA ---
            bf16x8 af[4], bfr[2];
            #pragma unroll
            for (int m = 0; m < 4; ++m)
                af[m] = *(const bf16x8*)&Al[((wr >> 4) + m) * 512 + lg * 128 + l16 * 8];
            #pragma unroll
            for (int n = 0; n < 2; ++n)
                bfr[n] = *(const bf16x8*)&Bl[((wc >> 4) + n) * 512 + lg * 128 + l16 * 8];
            #pragma unroll
            for (int m = 0; m < 4; ++m)
                #pragma unroll
                for (int n = 0; n < 2; ++n)
                    acc[m][n] = __builtin_amdgcn_mfma_f32_16x16x32_bf16(af[m], bfr[n], acc[m][n], 0, 0, 0);
        }
    }

    // --- epilogue: D reg j -> row (lg*4+j), col l16 ---
    #pragma unroll
    for (int m = 0; m < 4; ++m) {
        int rbase = r0 + wr + m * 16 + lg * 4;
        #pragma unroll
        for (int n = 0; n < 2; ++n) {
            int c = c0 + wc + n * 16 + l16;
            #pragma unroll
            for (int j = 0; j < 4; ++j) {
                int r = rbase + j;
                float v = acc[m][n][j];
                if (BIAS_MODE == 1) v += bias[c];
                else if (BIAS_MODE == 2) v += bias[(r >> 13) * ldbias + c];
                if (LEAKY) v = LRELU(v);
                if (RESID) v += resid[(size_t)r * ldres + c];
                C[(size_t)r * ldc + c] = v;
            }
        }
    }
}

// ---------------- final head ----------------
__global__ void out_kernel(const float* __restrict__ rbuf, const float* __restrict__ outW,
                           const float* __restrict__ outb, float* __restrict__ out) {
    int wid = (int)((blockIdx.x * blockDim.x + threadIdx.x) >> 6);
    int lane = threadIdx.x & 63;
    if (wid >= ROWS) return;
    const float* rr = rbuf + (long)wid * 512;
    float a0 = 0.f, a1 = 0.f, a2 = 0.f;
    for (int k = lane; k < 512; k += 64) {
        float x = rr[k];
        a0 += x * outW[k];
        a1 += x * outW[512 + k];
        a2 += x * outW[1024 + k];
    }
    #pragma unroll
    for (int off = 32; off; off >>= 1) {
        a0 += __shfl_down(a0, off);
        a1 += __shfl_down(a1, off);
        a2 += __shfl_down(a2, off);
    }
    if (lane == 0) {
        int b = wid >> 13, n = wid & 8191;
        float* ob = out + (long)b * 3 * 8192 + n;
        ob[0]        = 1.1f / (1.f + expf(-(a0 + outb[0]))) - 0.05f;
        ob[8192]     = 1.1f / (1.f + expf(-(a1 + outb[1]))) - 0.05f;
        ob[2 * 8192] = 1.1f / (1.f + expf(-(a2 + outb[2]))) - 0.05f;
    }
}

extern "C" void kernel_launch(void* const* d_in, const int* in_sizes, int n_in,
                              void* d_out, int out_size, void* d_ws, size_t ws_size,
                              hipStream_t stream) {
    const float* feature = (const float*)d_in[0];
    const float* points  = (const float*)d_in[1];
    const float* cw1 = (const float*)d_in[2];  const float* cb1 = (const float*)d_in[3];
    const float* cw2 = (const float*)d_in[4];  const float* cb2 = (const float*)d_in[5];
    const float* cw3 = (const float*)d_in[6];  const float* cb3 = (const float*)d_in[7];
    const float* cw4 = (const float*)d_in[8];  const float* cb4 = (const float*)d_in[9];
    const float* cw5 = (const float*)d_in[10]; const float* cb5 = (const float*)d_in[11];
    const float* lin1_W = (const float*)d_in[12]; const float* lin1_b = (const float*)d_in[13];
    const float* m1_Wf = (const float*)d_in[14]; const float* m1_bf = (const float*)d_in[15];
    const float* m1_Wg = (const float*)d_in[16]; const float* m1_bg = (const float*)d_in[17];
    const float* lin2_W = (const float*)d_in[18]; const float* lin2_b = (const float*)d_in[19];
    const float* m2_Wf = (const float*)d_in[20]; const float* m2_bf = (const float*)d_in[21];
    const float* m2_Wg = (const float*)d_in[22]; const float* m2_bg = (const float*)d_in[23];
    const float* out_W = (const float*)d_in[24]; const float* out_b = (const float*)d_in[25];
    float* out = (float*)d_out;

    // workspace (floats): pe | h | rb ; conv scratch + feat + base1 overlay rb; bf16 weights after
    float* ws = (float*)d_ws;
    float* pe = ws;                               // 32768*32
    float* h  = pe + (size_t)ROWS * 32;           // 32768*1024
    float* rb = h + (size_t)ROWS * 1024;          // 32768*512
    float* xA = rb;
    float* xB = rb + 204800;
    float* feat  = rb + 409600;                   // 4*2048
    float* base1 = rb + 417792;                   // 4*1024
    short* wsb  = (short*)(rb + (size_t)ROWS * 512);
    short* w1pe = wsb;                            // 1024*32
    short* w2   = w1pe + 1024 * 32;               // 512*1056
    short* m1wf = w2 + 512 * 1056;                // 8*512*512
    short* m1wg = m1wf + (size_t)8 * 512 * 512;
    short* m2wf = m1wg + (size_t)8 * 512 * 512;   // 8*256*256
    short* m2wg = m2wf + (size_t)8 * 256 * 256;

    // ---- weight conversions ----
    {
        int n;
        n = 8 * 512 * 512 / 4;
        cvt_bf16_kernel<<<(n + 255) / 256, 256, 0, stream>>>(m1_Wf, m1wf, n);
        cvt_bf16_kernel<<<(n + 255) / 256, 256, 0, stream>>>(m1_Wg, m1wg, n);
        n = 8 * 256 * 256 / 4;
        cvt_bf16_kernel<<<(n + 255) / 256, 256, 0, stream>>>(m2_Wf, m2wf, n);
        cvt_bf16_kernel<<<(n + 255) / 256, 256, 0, stream>>>(m2_Wg, m2wg, n);
        n = 512 * 1056 / 4;
        cvt_bf16_kernel<<<(n + 255) / 256, 256, 0, stream>>>(lin2_W, w2, n);
        cvt_w1pe_kernel<<<(1024 * 32 + 255) / 256, 256, 0, stream>>>(lin1_W, w1pe);
    }

    // ---- conv stack ----
    {
        int t1 = 4 * 768 * 64;
        conv3x3_kernel<<<(t1 + 255) / 256, 256, 0, stream>>>(feature, cw1, cb1, xA, 4, 1792, 768, 8, 8, 1, 4);
        conv3x3_kernel<<<(t1 + 255) / 256, 256, 0, stream>>>(xA, cw2, cb2, xB, 4, 768, 768, 8, 8, 1, 3);
        conv3x3_kernel<<<(t1 + 255) / 256, 256, 0, stream>>>(xB, cw3, cb3, xA, 4, 768, 768, 8, 8, 1, 2);
        int t4 = 4 * 768 * 36;
        conv3x3_kernel<<<(t4 + 255) / 256, 256, 0, stream>>>(xA, cw4, cb4, xB, 4, 768, 768, 8, 8, 0, 3);
        int t5 = 4 * 128 * 16;
        conv3x3_kernel<<<(t5 + 255) / 256, 256, 0, stream>>>(xB, cw5, cb5, feat, 4, 768, 128, 6, 6, 0, 1);
    }

    base1_kernel<<<(BATCH * 1024 * 64) / 256, 256, 0, stream>>>(feat, lin1_W, lin1_b, base1);
    pe_kernel<<<(ROWS * 32) / 256, 256, 0, stream>>>(points, pe, ROWS * 32);

    // ---- lin1: h = leaky(pe @ w1pe.T + base1[batch]) ----
    {
        dim3 g(1024 / 64, ROWS / 128);
        mgemm<2, true, false><<<g, 256, 0, stream>>>(
            pe, 32, 32, nullptr, 0, 0, w1pe, 32, base1, 1024, h, 1024, nullptr, 0);
    }

    // ---- 8 couplings on 1024-wide h ----
    for (int s = 0; s < 8; ++s) {
        const short* Wf = m1wf + (size_t)s * 512 * 512;
        const float* bf = m1_bf + (size_t)s * 512;
        const short* Wg = m1wg + (size_t)s * 512 * 512;
        const float* bg = m1_bg + (size_t)s * 512;
        dim3 g(512 / 64, ROWS / 128);
        mgemm<1, true, true><<<g, 256, 0, stream>>>(
            h + 512, 1024, 512, nullptr, 0, 0, Wf, 512, bf, 0, h, 1024, h, 1024);
        mgemm<1, true, true><<<g, 256, 0, stream>>>(
            h, 1024, 512, nullptr, 0, 0, Wg, 512, bg, 0, h + 512, 1024, h + 512, 1024);
    }

    // ---- lin2: r = leaky([pe, h] @ w2.T + lin2_b) ----
    {
        dim3 g(512 / 64, ROWS / 128);
        mgemm<1, true, false><<<g, 256, 0, stream>>>(
            pe, 32, 32, h, 1024, 1024, w2, 1056, lin2_b, 0, rb, 512, nullptr, 0);
    }

    // ---- 8 couplings on 512-wide r ----
    for (int s = 0; s < 8; ++s) {
        const short* Wf = m2wf + (size_t)s * 256 * 256;
        const float* bf = m2_bf + (size_t)s * 256;
        const short* Wg = m2wg + (size_t)s * 256 * 256;
        const float* bg = m2_bg + (size_t)s * 256;
        dim3 g(256 / 64, ROWS / 128);
        mgemm<1, true, true><<<g, 256, 0, stream>>>(
            rb + 256, 512, 256, nullptr, 0, 0, Wf, 256, bf, 0, rb, 512, rb, 512);
        mgemm<1, true, true><<<g, 256, 0, stream>>>(
            rb, 512, 256, nullptr, 0, 0, Wg, 256, bg, 0, rb + 256, 512, rb + 256, 512);
    }

    out_kernel<<<(ROWS * 64) / 256, 256, 0, stream>>>(rb, out_W, out_b, out);
}

// Round 5
// 3200.168 us; speedup vs baseline: 1.3201x; 1.3201x over previous
//
#include <hip/hip_runtime.h>
#include <math.h>

// DecoderCenter — Round 5: R4 (im2col + split-bf16 conv GEMM) with the compile fix:
// split2 returns packed u32 (hi|lo<<16) instead of binding refs to vector elements.

#define LRELU(v) ((v) >= 0.0f ? (v) : 0.01f * (v))

static constexpr int BATCH = 4;
static constexpr int NPTS  = 8192;
static constexpr int ROWS  = BATCH * NPTS;   // 32768

typedef short bf16x8 __attribute__((ext_vector_type(8)));
typedef float f32x4  __attribute__((ext_vector_type(4)));

// fp32 -> bf16 (RNE)
static __device__ __forceinline__ short f2bf(float f) {
    unsigned u = __float_as_uint(f);
    unsigned r = (u + 0x7fffu + ((u >> 16) & 1u)) >> 16;
    return (short)r;
}
// hi = bf16(v), lo = bf16(v - hi); packed as hi | (lo<<16)
static __device__ __forceinline__ unsigned split2u(float v) {
    unsigned hi = (unsigned)(unsigned short)f2bf(v);
    float hf = __uint_as_float(hi << 16);
    unsigned lo = (unsigned)(unsigned short)f2bf(v - hf);
    return hi | (lo << 16);
}

// ---------------- im2col (fp32, per-batch rows padded to 64) ----------------
// col[(g*256 + b*64 + hw) * K + ic*9 + kh*3 + kw]
__global__ void im2col_kernel(const float* __restrict__ in, float* __restrict__ col,
                              int Cin, int Hi, int Wi, int Ho, int Wo,
                              int pad, int CinG, int K, int G) {
    int idx = blockIdx.x * blockDim.x + threadIdx.x;
    int total = G * 256 * K;
    if (idx >= total) return;
    int k = idx % K; int t = idx / K;
    int row = t & 255; int g = t >> 8;
    int b = row >> 6, hw = row & 63;
    int oh = hw / Wo, ow = hw - oh * Wo;
    int ic = k / 9, r9 = k - ic * 9;
    int kh = r9 / 3, kw = r9 - kh * 3;
    int ih = oh + kh - pad, iw = ow + kw - pad;
    float v = 0.f;
    if (hw < Ho * Wo && (unsigned)ih < (unsigned)Hi && (unsigned)iw < (unsigned)Wi)
        v = in[((long)(b * Cin + g * CinG + ic) * Hi + ih) * Wi + iw];
    col[idx] = v;
}

// ---------------- conv as GEMM: 3-term bf16 split (~fp32 precision) ----------------
// A: fp32 im2col [G][256][K]; W: fp32 [Cout][K] (group g rows contiguous).
// C: NCHW fp32 [B][Cout][HWo]. BM=128, BN=64, BK=32, 4 waves.
__global__ __launch_bounds__(256) void conv_mgemm(
    const float* __restrict__ A, const float* __restrict__ W, int K,
    const float* __restrict__ bias, float* __restrict__ C,
    int Cout, int HWo, int OG)
{
    __shared__ short Ah[128 * 32], Alo[128 * 32];
    __shared__ short Bh[64 * 32],  Blo[64 * 32];
    const int r0 = blockIdx.y * 128, c0 = blockIdx.x * 64;
    const float* Ag = A + (size_t)(c0 / OG) * 256 * K;
    const int tid = threadIdx.x;
    const int lane = tid & 63, w = tid >> 6;
    const int wr = (w >> 1) * 64, wc = (w & 1) * 32;
    const int l16 = lane & 15, lg = lane >> 4;

    f32x4 acc[4][2] = {};
    const int sar = tid >> 1, sak = (tid & 1) * 16;
    const int sbc = tid >> 2, sbk = tid & 3;

    for (int kt = 0; kt < K; kt += 32) {
        __syncthreads();
        {   // stage A (fp32 -> hi/lo bf16)
            const float* ap = Ag + (size_t)(r0 + sar) * K + kt + sak;
            bf16x8 h0, h1, L0, L1;
            #pragma unroll
            for (int q = 0; q < 2; ++q) {
                float4 va = *(const float4*)(ap + q * 8);
                float4 vb = *(const float4*)(ap + q * 8 + 4);
                unsigned p;
                #define SPL(vec, dst_h, dst_l, i0) \
                    p = split2u(vec.x); dst_h[i0+0] = (short)p; dst_l[i0+0] = (short)(p >> 16); \
                    p = split2u(vec.y); dst_h[i0+1] = (short)p; dst_l[i0+1] = (short)(p >> 16); \
                    p = split2u(vec.z); dst_h[i0+2] = (short)p; dst_l[i0+2] = (short)(p >> 16); \
                    p = split2u(vec.w); dst_h[i0+3] = (short)p; dst_l[i0+3] = (short)(p >> 16);
                if (q == 0) { SPL(va, h0, L0, 0) SPL(vb, h0, L0, 4) }
                else        { SPL(va, h1, L1, 0) SPL(vb, h1, L1, 4) }
            }
            int base = ((sar >> 4) * 4 + (sak >> 3)) * 128 + (sar & 15) * 8;
            *(bf16x8*)&Ah[base]        = h0; *(bf16x8*)&Ah[base + 128]  = h1;
            *(bf16x8*)&Alo[base]       = L0; *(bf16x8*)&Alo[base + 128] = L1;
        }
        {   // stage B (weights fp32 -> hi/lo bf16)
            const float* bp = W + (size_t)(c0 + sbc) * K + kt + sbk * 8;
            float4 va = *(const float4*)(bp);
            float4 vb = *(const float4*)(bp + 4);
            bf16x8 hh, ll;
            unsigned p;
            SPL(va, hh, ll, 0) SPL(vb, hh, ll, 4)
            #undef SPL
            int base = ((sbc >> 4) * 4 + sbk) * 128 + (sbc & 15) * 8;
            *(bf16x8*)&Bh[base] = hh; *(bf16x8*)&Blo[base] = ll;
        }
        __syncthreads();
        bf16x8 ah[4], al[4], bh[2], bl[2];
        #pragma unroll
        for (int m = 0; m < 4; ++m) {
            int o = ((wr >> 4) + m) * 512 + lg * 128 + l16 * 8;
            ah[m] = *(const bf16x8*)&Ah[o];
            al[m] = *(const bf16x8*)&Alo[o];
        }
        #pragma unroll
        for (int n = 0; n < 2; ++n) {
            int o = ((wc >> 4) + n) * 512 + lg * 128 + l16 * 8;
            bh[n] = *(const bf16x8*)&Bh[o];
            bl[n] = *(const bf16x8*)&Blo[o];
        }
        #pragma unroll
        for (int m = 0; m < 4; ++m)
            #pragma unroll
            for (int n = 0; n < 2; ++n) {
                acc[m][n] = __builtin_amdgcn_mfma_f32_16x16x32_bf16(ah[m], bh[n], acc[m][n], 0, 0, 0);
                acc[m][n] = __builtin_amdgcn_mfma_f32_16x16x32_bf16(al[m], bh[n], acc[m][n], 0, 0, 0);
                acc[m][n] = __builtin_amdgcn_mfma_f32_16x16x32_bf16(ah[m], bl[n], acc[m][n], 0, 0, 0);
            }
    }

    #pragma unroll
    for (int m = 0; m < 4; ++m) {
        int rbase = r0 + wr + m * 16 + lg * 4;
        #pragma unroll
        for (int n = 0; n < 2; ++n) {
            int c = c0 + wc + n * 16 + l16;
            #pragma unroll
            for (int j = 0; j < 4; ++j) {
                int r = rbase + j;
                int b = r >> 6, hw = r & 63;
                if (hw < HWo) {
                    float v = acc[m][n][j] + bias[c];
                    v = LRELU(v);
                    C[((size_t)b * Cout + c) * HWo + hw] = v;
                }
            }
        }
    }
}

// ---------------- positional encoding ----------------
__global__ void pe_kernel(const float* __restrict__ points, float* __restrict__ pe, int total) {
    int idx = blockIdx.x * blockDim.x + threadIdx.x;
    if (idx >= total) return;
    int j = idx & 31;
    int r = idx >> 5;
    int oct = j >> 1, c = j & 1;
    float f = exp2f(0.5f * (float)oct);
    pe[idx] = sinf(points[r * 2 + c] * f);
}

// ---------------- base1[b,o] = lin1_b[o] + feat[b,:] @ lin1_W[o, 32:2080] ----------------
__global__ void base1_kernel(const float* __restrict__ feat, const float* __restrict__ W,
                             const float* __restrict__ b, float* __restrict__ base) {
    int wid = (int)((blockIdx.x * blockDim.x + threadIdx.x) >> 6);
    int lane = threadIdx.x & 63;
    if (wid >= BATCH * 1024) return;
    int bb = wid >> 10, oc = wid & 1023;
    const float* fr = feat + bb * 2048;
    const float* wr = W + (long)oc * 2080 + 32;
    float acc = 0.f;
    for (int k = lane; k < 2048; k += 64) acc += fr[k] * wr[k];
    #pragma unroll
    for (int off = 32; off; off >>= 1) acc += __shfl_down(acc, off);
    if (lane == 0) base[wid] = acc + b[oc];
}

// ---------------- weight conversion fp32 -> bf16 ----------------
__global__ void cvt_bf16_kernel(const float* __restrict__ in, short* __restrict__ out, int n4) {
    int i = blockIdx.x * blockDim.x + threadIdx.x;
    if (i >= n4) return;
    float4 v = *(const float4*)(in + (size_t)i * 4);
    short4 s;
    s.x = f2bf(v.x); s.y = f2bf(v.y); s.z = f2bf(v.z); s.w = f2bf(v.w);
    *(short4*)(out + (size_t)i * 4) = s;
}

__global__ void cvt_w1pe_kernel(const float* __restrict__ W, short* __restrict__ out) {
    int i = blockIdx.x * blockDim.x + threadIdx.x;
    if (i >= 1024 * 32) return;
    int r = i >> 5, c = i & 31;
    out[i] = f2bf(W[(size_t)r * 2080 + c]);
}

// ---------------- bf16-MFMA GEMM, fused epilogue (unchanged from R3, passed) ----------------
template<int BIAS_MODE, bool LEAKY, bool RESID>
__global__ __launch_bounds__(256) void mgemm(
    const float* __restrict__ A1, int lda1, int K1,
    const float* __restrict__ A2, int lda2, int K2,
    const short* __restrict__ W, int ldw,
    const float* __restrict__ bias, int ldbias,
    float* __restrict__ C, int ldc,
    const float* __restrict__ resid, int ldres)
{
    __shared__ short Al[128 * 32];
    __shared__ short Bl[64 * 32];
    const int r0 = blockIdx.y * 128, c0 = blockIdx.x * 64;
    const int tid = threadIdx.x;
    const int lane = tid & 63, w = tid >> 6;
    const int wr = (w >> 1) * 64, wc = (w & 1) * 32;
    const int l16 = lane & 15, lg = lane >> 4;

    f32x4 acc[4][2] = {};
    const int sar = tid >> 1, sak = (tid & 1) * 16;
    const int sbc = tid >> 2, sbk = tid & 3;

    for (int src = 0; src < 2; ++src) {
        const float* A = src ? A2 : A1;
        const int K   = src ? K2 : K1;
        const int lda = src ? lda2 : lda1;
        const int kb  = src ? K1 : 0;
        if (K == 0) continue;
        for (int kt = 0; kt < K; kt += 32) {
            __syncthreads();
            {
                const float* ap = A + (size_t)(r0 + sar) * lda + kt + sak;
                float4 v0 = *(const float4*)(ap + 0);
                float4 v1 = *(const float4*)(ap + 4);
                float4 v2 = *(const float4*)(ap + 8);
                float4 v3 = *(const float4*)(ap + 12);
                bf16x8 s0, s1;
                s0[0] = f2bf(v0.x); s0[1] = f2bf(v0.y); s0[2] = f2bf(v0.z); s0[3] = f2bf(v0.w);
                s0[4] = f2bf(v1.x); s0[5] = f2bf(v1.y); s0[6] = f2bf(v1.z); s0[7] = f2bf(v1.w);
                s1[0] = f2bf(v2.x); s1[1] = f2bf(v2.y); s1[2] = f2bf(v2.z); s1[3] = f2bf(v2.w);
                s1[4] = f2bf(v3.x); s1[5] = f2bf(v3.y); s1[6] = f2bf(v3.z); s1[7] = f2bf(v3.w);
                int base = ((sar >> 4) * 4 + (sak >> 3)) * 128 + (sar & 15) * 8;
                *(bf16x8*)&Al[base]       = s0;
                *(bf16x8*)&Al[base + 128] = s1;
            }
            {
                const short* bp = W + (size_t)(c0 + sbc) * ldw + kb + kt + sbk * 8;
                bf16x8 bv = *(const bf16x8*)bp;
                *(bf16x8*)&Bl[((sbc >> 4) * 4 + sbk) * 128 + (sbc & 15) * 8] = bv;
            }
            __syncthreads();
            bf16x8 af[4], bfr[2];
            #pragma unroll
            for (int m = 0; m < 4; ++m)
                af[m] = *(const bf16x8*)&Al[((wr >> 4) + m) * 512 + lg * 128 + l16 * 8];
            #pragma unroll
            for (int n = 0; n < 2; ++n)
                bfr[n] = *(const bf16x8*)&Bl[((wc >> 4) + n) * 512 + lg * 128 + l16 * 8];
            #pragma unroll
            for (int m = 0; m < 4; ++m)
                #pragma unroll
                for (int n = 0; n < 2; ++n)
                    acc[m][n] = __builtin_amdgcn_mfma_f32_16x16x32_bf16(af[m], bfr[n], acc[m][n], 0, 0, 0);
        }
    }

    #pragma unroll
    for (int m = 0; m < 4; ++m) {
        int rbase = r0 + wr + m * 16 + lg * 4;
        #pragma unroll
        for (int n = 0; n < 2; ++n) {
            int c = c0 + wc + n * 16 + l16;
            #pragma unroll
            for (int j = 0; j < 4; ++j) {
                int r = rbase + j;
                float v = acc[m][n][j];
                if (BIAS_MODE == 1) v += bias[c];
                else if (BIAS_MODE == 2) v += bias[(r >> 13) * ldbias + c];
                if (LEAKY) v = LRELU(v);
                if (RESID) v += resid[(size_t)r * ldres + c];
                C[(size_t)r * ldc + c] = v;
            }
        }
    }
}

// ---------------- final head ----------------
__global__ void out_kernel(const float* __restrict__ rbuf, const float* __restrict__ outW,
                           const float* __restrict__ outb, float* __restrict__ out) {
    int wid = (int)((blockIdx.x * blockDim.x + threadIdx.x) >> 6);
    int lane = threadIdx.x & 63;
    if (wid >= ROWS) return;
    const float* rr = rbuf + (long)wid * 512;
    float a0 = 0.f, a1 = 0.f, a2 = 0.f;
    for (int k = lane; k < 512; k += 64) {
        float x = rr[k];
        a0 += x * outW[k];
        a1 += x * outW[512 + k];
        a2 += x * outW[1024 + k];
    }
    #pragma unroll
    for (int off = 32; off; off >>= 1) {
        a0 += __shfl_down(a0, off);
        a1 += __shfl_down(a1, off);
        a2 += __shfl_down(a2, off);
    }
    if (lane == 0) {
        int b = wid >> 13, n = wid & 8191;
        float* ob = out + (long)b * 3 * 8192 + n;
        ob[0]        = 1.1f / (1.f + expf(-(a0 + outb[0]))) - 0.05f;
        ob[8192]     = 1.1f / (1.f + expf(-(a1 + outb[1]))) - 0.05f;
        ob[2 * 8192] = 1.1f / (1.f + expf(-(a2 + outb[2]))) - 0.05f;
    }
}

extern "C" void kernel_launch(void* const* d_in, const int* in_sizes, int n_in,
                              void* d_out, int out_size, void* d_ws, size_t ws_size,
                              hipStream_t stream) {
    const float* feature = (const float*)d_in[0];
    const float* points  = (const float*)d_in[1];
    const float* cw1 = (const float*)d_in[2];  const float* cb1 = (const float*)d_in[3];
    const float* cw2 = (const float*)d_in[4];  const float* cb2 = (const float*)d_in[5];
    const float* cw3 = (const float*)d_in[6];  const float* cb3 = (const float*)d_in[7];
    const float* cw4 = (const float*)d_in[8];  const float* cb4 = (const float*)d_in[9];
    const float* cw5 = (const float*)d_in[10]; const float* cb5 = (const float*)d_in[11];
    const float* lin1_W = (const float*)d_in[12]; const float* lin1_b = (const float*)d_in[13];
    const float* m1_Wf = (const float*)d_in[14]; const float* m1_bf = (const float*)d_in[15];
    const float* m1_Wg = (const float*)d_in[16]; const float* m1_bg = (const float*)d_in[17];
    const float* lin2_W = (const float*)d_in[18]; const float* lin2_b = (const float*)d_in[19];
    const float* m2_Wf = (const float*)d_in[20]; const float* m2_bf = (const float*)d_in[21];
    const float* m2_Wg = (const float*)d_in[22]; const float* m2_bg = (const float*)d_in[23];
    const float* out_W = (const float*)d_in[24]; const float* out_b = (const float*)d_in[25];
    float* out = (float*)d_out;

    // workspace (floats): pe | h | rb ; conv-phase buffers overlay rb (dead by lin2)
    float* ws = (float*)d_ws;
    float* pe = ws;                               // 32768*32
    float* h  = pe + (size_t)ROWS * 32;           // 32768*1024
    float* rb = h + (size_t)ROWS * 1024;          // 32768*512
    float* xA = rb;                               // NCHW scratch (196608 f)
    float* xB = rb + 204800;                      // ends 401408
    float* feat  = rb + 409600;                   // 4*2048
    float* base1 = rb + 417792;                   // 4*1024
    float* colb  = rb + 500000;                   // im2col, max 4,128,768 f
    short* wsb  = (short*)(rb + (size_t)ROWS * 512);
    short* w1pe = wsb;                            // 1024*32
    short* w2   = w1pe + 1024 * 32;               // 512*1056
    short* m1wf = w2 + 512 * 1056;                // 8*512*512
    short* m1wg = m1wf + (size_t)8 * 512 * 512;
    short* m2wf = m1wg + (size_t)8 * 512 * 512;   // 8*256*256
    short* m2wg = m2wf + (size_t)8 * 256 * 256;

    // ---- chain weight conversions ----
    {
        int n;
        n = 8 * 512 * 512 / 4;
        cvt_bf16_kernel<<<(n + 255) / 256, 256, 0, stream>>>(m1_Wf, m1wf, n);
        cvt_bf16_kernel<<<(n + 255) / 256, 256, 0, stream>>>(m1_Wg, m1wg, n);
        n = 8 * 256 * 256 / 4;
        cvt_bf16_kernel<<<(n + 255) / 256, 256, 0, stream>>>(m2_Wf, m2wf, n);
        cvt_bf16_kernel<<<(n + 255) / 256, 256, 0, stream>>>(m2_Wg, m2wg, n);
        n = 512 * 1056 / 4;
        cvt_bf16_kernel<<<(n + 255) / 256, 256, 0, stream>>>(lin2_W, w2, n);
        cvt_w1pe_kernel<<<(1024 * 32 + 255) / 256, 256, 0, stream>>>(lin1_W, w1pe);
    }

    // ---- conv stack: im2col + split-bf16 MFMA GEMM per layer ----
    auto layer = [&](const float* in, const float* wt, const float* bias, float* outp,
                     int Cin, int Hi, int Wi, int Ho, int Wo, int pad, int G, int Cout) {
        int CinG = Cin / G, K = CinG * 9, OG = Cout / G;
        int total = G * 256 * K;
        im2col_kernel<<<(total + 255) / 256, 256, 0, stream>>>(
            in, colb, Cin, Hi, Wi, Ho, Wo, pad, CinG, K, G);
        dim3 g(Cout / 64, 2);
        conv_mgemm<<<g, 256, 0, stream>>>(colb, wt, K, bias, outp, Cout, Ho * Wo, OG);
    };
    layer(feature, cw1, cb1, xA, 1792, 8, 8, 8, 8, 1, 4, 768);
    layer(xA, cw2, cb2, xB, 768, 8, 8, 8, 8, 1, 3, 768);
    layer(xB, cw3, cb3, xA, 768, 8, 8, 8, 8, 1, 2, 768);
    layer(xA, cw4, cb4, xB, 768, 8, 8, 6, 6, 0, 3, 768);
    layer(xB, cw5, cb5, feat, 768, 6, 6, 4, 4, 0, 1, 128);

    base1_kernel<<<(BATCH * 1024 * 64) / 256, 256, 0, stream>>>(feat, lin1_W, lin1_b, base1);
    pe_kernel<<<(ROWS * 32) / 256, 256, 0, stream>>>(points, pe, ROWS * 32);

    // ---- lin1 ----
    {
        dim3 g(1024 / 64, ROWS / 128);
        mgemm<2, true, false><<<g, 256, 0, stream>>>(
            pe, 32, 32, nullptr, 0, 0, w1pe, 32, base1, 1024, h, 1024, nullptr, 0);
    }

    // ---- 8 couplings on 1024-wide h ----
    for (int s = 0; s < 8; ++s) {
        const short* Wf = m1wf + (size_t)s * 512 * 512;
        const float* bf = m1_bf + (size_t)s * 512;
        const short* Wg = m1wg + (size_t)s * 512 * 512;
        const float* bg = m1_bg + (size_t)s * 512;
        dim3 g(512 / 64, ROWS / 128);
        mgemm<1, true, true><<<g, 256, 0, stream>>>(
            h + 512, 1024, 512, nullptr, 0, 0, Wf, 512, bf, 0, h, 1024, h, 1024);
        mgemm<1, true, true><<<g, 256, 0, stream>>>(
            h, 1024, 512, nullptr, 0, 0, Wg, 512, bg, 0, h + 512, 1024, h + 512, 1024);
    }

    // ---- lin2 ----
    {
        dim3 g(512 / 64, ROWS / 128);
        mgemm<1, true, false><<<g, 256, 0, stream>>>(
            pe, 32, 32, h, 1024, 1024, w2, 1056, lin2_b, 0, rb, 512, nullptr, 0);
    }

    // ---- 8 couplings on 512-wide r ----
    for (int s = 0; s < 8; ++s) {
        const short* Wf = m2wf + (size_t)s * 256 * 256;
        const float* bf = m2_bf + (size_t)s * 256;
        const short* Wg = m2wg + (size_t)s * 256 * 256;
        const float* bg = m2_bg + (size_t)s * 256;
        dim3 g(256 / 64, ROWS / 128);
        mgemm<1, true, true><<<g, 256, 0, stream>>>(
            rb + 256, 512, 256, nullptr, 0, 0, Wf, 256, bf, 0, rb, 512, rb, 512);
        mgemm<1, true, true><<<g, 256, 0, stream>>>(
            rb, 512, 256, nullptr, 0, 0, Wg, 256, bg, 0, rb + 256, 512, rb + 256, 512);
    }

    out_kernel<<<(ROWS * 64) / 256, 256, 0, stream>>>(rb, out_W, out_b, out);
}

// Round 7
// 2418.614 us; speedup vs baseline: 1.7467x; 1.3231x over previous
//
#include <hip/hip_runtime.h>
#include <math.h>

// DecoderCenter — Round 7: R6 split-K conv with the reduce-grid bug fixed
// (Cout=128 layer got grid.x = 128/256 = 0 -> feat never written, absmax 0.107).
// Now gr.x = ceil(Cout/256) + c<Cout guard.

#define LRELU(v) ((v) >= 0.0f ? (v) : 0.01f * (v))

static constexpr int BATCH = 4;
static constexpr int NPTS  = 8192;
static constexpr int ROWS  = BATCH * NPTS;   // 32768

typedef short bf16x8 __attribute__((ext_vector_type(8)));
typedef float f32x4  __attribute__((ext_vector_type(4)));

// fp32 -> bf16 (RNE)
static __device__ __forceinline__ short f2bf(float f) {
    unsigned u = __float_as_uint(f);
    unsigned r = (u + 0x7fffu + ((u >> 16) & 1u)) >> 16;
    return (short)r;
}
// hi = bf16(v), lo = bf16(v - hi); packed as hi | (lo<<16)
static __device__ __forceinline__ unsigned split2u(float v) {
    unsigned hi = (unsigned)(unsigned short)f2bf(v);
    float hf = __uint_as_float(hi << 16);
    unsigned lo = (unsigned)(unsigned short)f2bf(v - hf);
    return hi | (lo << 16);
}

// ---------------- im2col (fp32, per-batch rows padded to 64) ----------------
// col[(g*256 + b*64 + hw) * K + ic*9 + kh*3 + kw]
__global__ void im2col_kernel(const float* __restrict__ in, float* __restrict__ col,
                              int Cin, int Hi, int Wi, int Ho, int Wo,
                              int pad, int CinG, int K, int G) {
    int idx = blockIdx.x * blockDim.x + threadIdx.x;
    int total = G * 256 * K;
    if (idx >= total) return;
    int k = idx % K; int t = idx / K;
    int row = t & 255; int g = t >> 8;
    int b = row >> 6, hw = row & 63;
    int oh = hw / Wo, ow = hw - oh * Wo;
    int ic = k / 9, r9 = k - ic * 9;
    int kh = r9 / 3, kw = r9 - kh * 3;
    int ih = oh + kh - pad, iw = ow + kw - pad;
    float v = 0.f;
    if (hw < Ho * Wo && (unsigned)ih < (unsigned)Hi && (unsigned)iw < (unsigned)Wi)
        v = in[((long)(b * Cin + g * CinG + ic) * Hi + ih) * Wi + iw];
    col[idx] = v;
}

// ---------------- split-K conv GEMM: 3-term bf16 split, fp32 partials ----------------
__global__ __launch_bounds__(256) void conv_mgemm_splitk(
    const float* __restrict__ A, const float* __restrict__ W, int K, int Kc,
    float* __restrict__ partial, int Cout, int OG)
{
    __shared__ short Ah[128 * 32], Alo[128 * 32];
    __shared__ short Bh[64 * 32],  Blo[64 * 32];
    const int r0 = blockIdx.y * 128, c0 = blockIdx.x * 64;
    const int s = blockIdx.z;
    const int k0 = s * Kc;
    const int k1 = min(k0 + Kc, K);
    const float* Ag = A + (size_t)(c0 / OG) * 256 * K;
    const int tid = threadIdx.x;
    const int lane = tid & 63, w = tid >> 6;
    const int wr = (w >> 1) * 64, wc = (w & 1) * 32;
    const int l16 = lane & 15, lg = lane >> 4;

    f32x4 acc[4][2] = {};
    const int sar = tid >> 1, sak = (tid & 1) * 16;
    const int sbc = tid >> 2, sbk = tid & 3;

    for (int kt = k0; kt < k1; kt += 32) {
        __syncthreads();
        {   // stage A (fp32 -> hi/lo bf16)
            const float* ap = Ag + (size_t)(r0 + sar) * K + kt + sak;
            bf16x8 h0, h1, L0, L1;
            unsigned p;
            #define SPL(vec, dst_h, dst_l, i0) \
                p = split2u(vec.x); dst_h[i0+0] = (short)p; dst_l[i0+0] = (short)(p >> 16); \
                p = split2u(vec.y); dst_h[i0+1] = (short)p; dst_l[i0+1] = (short)(p >> 16); \
                p = split2u(vec.z); dst_h[i0+2] = (short)p; dst_l[i0+2] = (short)(p >> 16); \
                p = split2u(vec.w); dst_h[i0+3] = (short)p; dst_l[i0+3] = (short)(p >> 16);
            {
                float4 va = *(const float4*)(ap + 0);
                float4 vb = *(const float4*)(ap + 4);
                SPL(va, h0, L0, 0) SPL(vb, h0, L0, 4)
            }
            {
                float4 va = *(const float4*)(ap + 8);
                float4 vb = *(const float4*)(ap + 12);
                SPL(va, h1, L1, 0) SPL(vb, h1, L1, 4)
            }
            int base = ((sar >> 4) * 4 + (sak >> 3)) * 128 + (sar & 15) * 8;
            *(bf16x8*)&Ah[base]        = h0; *(bf16x8*)&Ah[base + 128]  = h1;
            *(bf16x8*)&Alo[base]       = L0; *(bf16x8*)&Alo[base + 128] = L1;
        }
        {   // stage B (weights fp32 -> hi/lo bf16)
            const float* bp = W + (size_t)(c0 + sbc) * K + kt + sbk * 8;
            float4 va = *(const float4*)(bp);
            float4 vb = *(const float4*)(bp + 4);
            bf16x8 hh, ll;
            unsigned p;
            SPL(va, hh, ll, 0) SPL(vb, hh, ll, 4)
            #undef SPL
            int base = ((sbc >> 4) * 4 + sbk) * 128 + (sbc & 15) * 8;
            *(bf16x8*)&Bh[base] = hh; *(bf16x8*)&Blo[base] = ll;
        }
        __syncthreads();
        bf16x8 ah[4], al[4], bh[2], bl[2];
        #pragma unroll
        for (int m = 0; m < 4; ++m) {
            int o = ((wr >> 4) + m) * 512 + lg * 128 + l16 * 8;
            ah[m] = *(const bf16x8*)&Ah[o];
            al[m] = *(const bf16x8*)&Alo[o];
        }
        #pragma unroll
        for (int n = 0; n < 2; ++n) {
            int o = ((wc >> 4) + n) * 512 + lg * 128 + l16 * 8;
            bh[n] = *(const bf16x8*)&Bh[o];
            bl[n] = *(const bf16x8*)&Blo[o];
        }
        #pragma unroll
        for (int m = 0; m < 4; ++m)
            #pragma unroll
            for (int n = 0; n < 2; ++n) {
                acc[m][n] = __builtin_amdgcn_mfma_f32_16x16x32_bf16(ah[m], bh[n], acc[m][n], 0, 0, 0);
                acc[m][n] = __builtin_amdgcn_mfma_f32_16x16x32_bf16(al[m], bh[n], acc[m][n], 0, 0, 0);
                acc[m][n] = __builtin_amdgcn_mfma_f32_16x16x32_bf16(ah[m], bl[n], acc[m][n], 0, 0, 0);
            }
    }

    float* pp = partial + (size_t)s * 256 * Cout;
    #pragma unroll
    for (int m = 0; m < 4; ++m) {
        int rbase = r0 + wr + m * 16 + lg * 4;
        #pragma unroll
        for (int n = 0; n < 2; ++n) {
            int c = c0 + wc + n * 16 + l16;
            #pragma unroll
            for (int j = 0; j < 4; ++j)
                pp[(size_t)(rbase + j) * Cout + c] = acc[m][n][j];
        }
    }
}

// ---------------- split-K reduce + bias + leaky + NCHW write ----------------
// grid (ceil(Cout/256), 256): blockIdx.y = row, c = blockIdx.x*256 + tid
__global__ void conv_reduce_kernel(const float* __restrict__ partial,
                                   const float* __restrict__ bias, float* __restrict__ C,
                                   int S, int Cout, int HWo) {
    int c = blockIdx.x * 256 + threadIdx.x;
    if (c >= Cout) return;
    int r = blockIdx.y;
    int b = r >> 6, hw = r & 63;
    if (hw >= HWo) return;
    float acc = bias[c];
    for (int s = 0; s < S; ++s)
        acc += partial[((size_t)s * 256 + r) * Cout + c];
    C[((size_t)b * Cout + c) * HWo + hw] = LRELU(acc);
}

// ---------------- positional encoding ----------------
__global__ void pe_kernel(const float* __restrict__ points, float* __restrict__ pe, int total) {
    int idx = blockIdx.x * blockDim.x + threadIdx.x;
    if (idx >= total) return;
    int j = idx & 31;
    int r = idx >> 5;
    int oct = j >> 1, c = j & 1;
    float f = exp2f(0.5f * (float)oct);
    pe[idx] = sinf(points[r * 2 + c] * f);
}

// ---------------- base1[b,o] = lin1_b[o] + feat[b,:] @ lin1_W[o, 32:2080] ----------------
__global__ void base1_kernel(const float* __restrict__ feat, const float* __restrict__ W,
                             const float* __restrict__ b, float* __restrict__ base) {
    int wid = (int)((blockIdx.x * blockDim.x + threadIdx.x) >> 6);
    int lane = threadIdx.x & 63;
    if (wid >= BATCH * 1024) return;
    int bb = wid >> 10, oc = wid & 1023;
    const float* fr = feat + bb * 2048;
    const float* wr = W + (long)oc * 2080 + 32;
    float acc = 0.f;
    for (int k = lane; k < 2048; k += 64) acc += fr[k] * wr[k];
    #pragma unroll
    for (int off = 32; off; off >>= 1) acc += __shfl_down(acc, off);
    if (lane == 0) base[wid] = acc + b[oc];
}

// ---------------- weight conversion fp32 -> bf16 ----------------
__global__ void cvt_bf16_kernel(const float* __restrict__ in, short* __restrict__ out, int n4) {
    int i = blockIdx.x * blockDim.x + threadIdx.x;
    if (i >= n4) return;
    float4 v = *(const float4*)(in + (size_t)i * 4);
    short4 s;
    s.x = f2bf(v.x); s.y = f2bf(v.y); s.z = f2bf(v.z); s.w = f2bf(v.w);
    *(short4*)(out + (size_t)i * 4) = s;
}

__global__ void cvt_w1pe_kernel(const float* __restrict__ W, short* __restrict__ out) {
    int i = blockIdx.x * blockDim.x + threadIdx.x;
    if (i >= 1024 * 32) return;
    int r = i >> 5, c = i & 31;
    out[i] = f2bf(W[(size_t)r * 2080 + c]);
}

// ---------------- bf16-MFMA GEMM, fused epilogue (unchanged, passing) ----------------
template<int BIAS_MODE, bool LEAKY, bool RESID>
__global__ __launch_bounds__(256) void mgemm(
    const float* __restrict__ A1, int lda1, int K1,
    const float* __restrict__ A2, int lda2, int K2,
    const short* __restrict__ W, int ldw,
    const float* __restrict__ bias, int ldbias,
    float* __restrict__ C, int ldc,
    const float* __restrict__ resid, int ldres)
{
    __shared__ short Al[128 * 32];
    __shared__ short Bl[64 * 32];
    const int r0 = blockIdx.y * 128, c0 = blockIdx.x * 64;
    const int tid = threadIdx.x;
    const int lane = tid & 63, w = tid >> 6;
    const int wr = (w >> 1) * 64, wc = (w & 1) * 32;
    const int l16 = lane & 15, lg = lane >> 4;

    f32x4 acc[4][2] = {};
    const int sar = tid >> 1, sak = (tid & 1) * 16;
    const int sbc = tid >> 2, sbk = tid & 3;

    for (int src = 0; src < 2; ++src) {
        const float* A = src ? A2 : A1;
        const int K   = src ? K2 : K1;
        const int lda = src ? lda2 : lda1;
        const int kb  = src ? K1 : 0;
        if (K == 0) continue;
        for (int kt = 0; kt < K; kt += 32) {
            __syncthreads();
            {
                const float* ap = A + (size_t)(r0 + sar) * lda + kt + sak;
                float4 v0 = *(const float4*)(ap + 0);
                float4 v1 = *(const float4*)(ap + 4);
                float4 v2 = *(const float4*)(ap + 8);
                float4 v3 = *(const float4*)(ap + 12);
                bf16x8 s0, s1;
                s0[0] = f2bf(v0.x); s0[1] = f2bf(v0.y); s0[2] = f2bf(v0.z); s0[3] = f2bf(v0.w);
                s0[4] = f2bf(v1.x); s0[5] = f2bf(v1.y); s0[6] = f2bf(v1.z); s0[7] = f2bf(v1.w);
                s1[0] = f2bf(v2.x); s1[1] = f2bf(v2.y); s1[2] = f2bf(v2.z); s1[3] = f2bf(v2.w);
                s1[4] = f2bf(v3.x); s1[5] = f2bf(v3.y); s1[6] = f2bf(v3.z); s1[7] = f2bf(v3.w);
                int base = ((sar >> 4) * 4 + (sak >> 3)) * 128 + (sar & 15) * 8;
                *(bf16x8*)&Al[base]       = s0;
                *(bf16x8*)&Al[base + 128] = s1;
            }
            {
                const short* bp = W + (size_t)(c0 + sbc) * ldw + kb + kt + sbk * 8;
                bf16x8 bv = *(const bf16x8*)bp;
                *(bf16x8*)&Bl[((sbc >> 4) * 4 + sbk) * 128 + (sbc & 15) * 8] = bv;
            }
            __syncthreads();
            bf16x8 af[4], bfr[2];
            #pragma unroll
            for (int m = 0; m < 4; ++m)
                af[m] = *(const bf16x8*)&Al[((wr >> 4) + m) * 512 + lg * 128 + l16 * 8];
            #pragma unroll
            for (int n = 0; n < 2; ++n)
                bfr[n] = *(const bf16x8*)&Bl[((wc >> 4) + n) * 512 + lg * 128 + l16 * 8];
            #pragma unroll
            for (int m = 0; m < 4; ++m)
                #pragma unroll
                for (int n = 0; n < 2; ++n)
                    acc[m][n] = __builtin_amdgcn_mfma_f32_16x16x32_bf16(af[m], bfr[n], acc[m][n], 0, 0, 0);
        }
    }

    #pragma unroll
    for (int m = 0; m < 4; ++m) {
        int rbase = r0 + wr + m * 16 + lg * 4;
        #pragma unroll
        for (int n = 0; n < 2; ++n) {
            int c = c0 + wc + n * 16 + l16;
            #pragma unroll
            for (int j = 0; j < 4; ++j) {
                int r = rbase + j;
                float v = acc[m][n][j];
                if (BIAS_MODE == 1) v += bias[c];
                else if (BIAS_MODE == 2) v += bias[(r >> 13) * ldbias + c];
                if (LEAKY) v = LRELU(v);
                if (RESID) v += resid[(size_t)r * ldres + c];
                C[(size_t)r * ldc + c] = v;
            }
        }
    }
}

// ---------------- final head ----------------
__global__ void out_kernel(const float* __restrict__ rbuf, const float* __restrict__ outW,
                           const float* __restrict__ outb, float* __restrict__ out) {
    int wid = (int)((blockIdx.x * blockDim.x + threadIdx.x) >> 6);
    int lane = threadIdx.x & 63;
    if (wid >= ROWS) return;
    const float* rr = rbuf + (long)wid * 512;
    float a0 = 0.f, a1 = 0.f, a2 = 0.f;
    for (int k = lane; k < 512; k += 64) {
        float x = rr[k];
        a0 += x * outW[k];
        a1 += x * outW[512 + k];
        a2 += x * outW[1024 + k];
    }
    #pragma unroll
    for (int off = 32; off; off >>= 1) {
        a0 += __shfl_down(a0, off);
        a1 += __shfl_down(a1, off);
        a2 += __shfl_down(a2, off);
    }
    if (lane == 0) {
        int b = wid >> 13, n = wid & 8191;
        float* ob = out + (long)b * 3 * 8192 + n;
        ob[0]        = 1.1f / (1.f + expf(-(a0 + outb[0]))) - 0.05f;
        ob[8192]     = 1.1f / (1.f + expf(-(a1 + outb[1]))) - 0.05f;
        ob[2 * 8192] = 1.1f / (1.f + expf(-(a2 + outb[2]))) - 0.05f;
    }
}

extern "C" void kernel_launch(void* const* d_in, const int* in_sizes, int n_in,
                              void* d_out, int out_size, void* d_ws, size_t ws_size,
                              hipStream_t stream) {
    const float* feature = (const float*)d_in[0];
    const float* points  = (const float*)d_in[1];
    const float* cw1 = (const float*)d_in[2];  const float* cb1 = (const float*)d_in[3];
    const float* cw2 = (const float*)d_in[4];  const float* cb2 = (const float*)d_in[5];
    const float* cw3 = (const float*)d_in[6];  const float* cb3 = (const float*)d_in[7];
    const float* cw4 = (const float*)d_in[8];  const float* cb4 = (const float*)d_in[9];
    const float* cw5 = (const float*)d_in[10]; const float* cb5 = (const float*)d_in[11];
    const float* lin1_W = (const float*)d_in[12]; const float* lin1_b = (const float*)d_in[13];
    const float* m1_Wf = (const float*)d_in[14]; const float* m1_bf = (const float*)d_in[15];
    const float* m1_Wg = (const float*)d_in[16]; const float* m1_bg = (const float*)d_in[17];
    const float* lin2_W = (const float*)d_in[18]; const float* lin2_b = (const float*)d_in[19];
    const float* m2_Wf = (const float*)d_in[20]; const float* m2_bf = (const float*)d_in[21];
    const float* m2_Wg = (const float*)d_in[22]; const float* m2_bg = (const float*)d_in[23];
    const float* out_W = (const float*)d_in[24]; const float* out_b = (const float*)d_in[25];
    float* out = (float*)d_out;

    // workspace (floats): pe | h | rb ; conv-phase buffers overlay rb (dead by lin2)
    float* ws = (float*)d_ws;
    float* pe = ws;                               // 32768*32
    float* h  = pe + (size_t)ROWS * 32;           // 32768*1024
    float* rb = h + (size_t)ROWS * 1024;          // 32768*512 (16.78M floats)
    float* xA = rb;                               // NCHW scratch (196608 f)
    float* xB = rb + 204800;                      // ends 401408
    float* feat  = rb + 409600;                   // 4*2048
    float* base1 = rb + 417792;                   // 4*1024
    float* colb  = rb + 500000;                   // im2col, max 4,128,768 f
    float* partial = rb + 4700000;                // split-K partials, max ~3.1M f
    short* wsb  = (short*)(rb + (size_t)ROWS * 512);
    short* w1pe = wsb;                            // 1024*32
    short* w2   = w1pe + 1024 * 32;               // 512*1056
    short* m1wf = w2 + 512 * 1056;                // 8*512*512
    short* m1wg = m1wf + (size_t)8 * 512 * 512;
    short* m2wf = m1wg + (size_t)8 * 512 * 512;   // 8*256*256
    short* m2wg = m2wf + (size_t)8 * 256 * 256;

    // ---- chain weight conversions ----
    {
        int n;
        n = 8 * 512 * 512 / 4;
        cvt_bf16_kernel<<<(n + 255) / 256, 256, 0, stream>>>(m1_Wf, m1wf, n);
        cvt_bf16_kernel<<<(n + 255) / 256, 256, 0, stream>>>(m1_Wg, m1wg, n);
        n = 8 * 256 * 256 / 4;
        cvt_bf16_kernel<<<(n + 255) / 256, 256, 0, stream>>>(m2_Wf, m2wf, n);
        cvt_bf16_kernel<<<(n + 255) / 256, 256, 0, stream>>>(m2_Wg, m2wg, n);
        n = 512 * 1056 / 4;
        cvt_bf16_kernel<<<(n + 255) / 256, 256, 0, stream>>>(lin2_W, w2, n);
        cvt_w1pe_kernel<<<(1024 * 32 + 255) / 256, 256, 0, stream>>>(lin1_W, w1pe);
    }

    // ---- conv stack: im2col + split-K MFMA GEMM + reduce per layer ----
    auto layer = [&](const float* in, const float* wt, const float* bias, float* outp,
                     int Cin, int Hi, int Wi, int Ho, int Wo, int pad, int G, int Cout) {
        int CinG = Cin / G, K = CinG * 9, OG = Cout / G;
        int total = G * 256 * K;
        im2col_kernel<<<(total + 255) / 256, 256, 0, stream>>>(
            in, colb, Cin, Hi, Wi, Ho, Wo, pad, CinG, K, G);
        int steps = K / 32;
        int S = (steps + 7) / 8;                 // ~8 K-steps per block
        int Kc = ((steps + S - 1) / S) * 32;
        dim3 g(Cout / 64, 2, S);
        conv_mgemm_splitk<<<g, 256, 0, stream>>>(colb, wt, K, Kc, partial, Cout, OG);
        dim3 gr((Cout + 255) / 256, 256);
        conv_reduce_kernel<<<gr, 256, 0, stream>>>(partial, bias, outp, S, Cout, Ho * Wo);
    };
    layer(feature, cw1, cb1, xA, 1792, 8, 8, 8, 8, 1, 4, 768);
    layer(xA, cw2, cb2, xB, 768, 8, 8, 8, 8, 1, 3, 768);
    layer(xB, cw3, cb3, xA, 768, 8, 8, 8, 8, 1, 2, 768);
    layer(xA, cw4, cb4, xB, 768, 8, 8, 6, 6, 0, 3, 768);
    layer(xB, cw5, cb5, feat, 768, 6, 6, 4, 4, 0, 1, 128);

    base1_kernel<<<(BATCH * 1024 * 64) / 256, 256, 0, stream>>>(feat, lin1_W, lin1_b, base1);
    pe_kernel<<<(ROWS * 32) / 256, 256, 0, stream>>>(points, pe, ROWS * 32);

    // ---- lin1 ----
    {
        dim3 g(1024 / 64, ROWS / 128);
        mgemm<2, true, false><<<g, 256, 0, stream>>>(
            pe, 32, 32, nullptr, 0, 0, w1pe, 32, base1, 1024, h, 1024, nullptr, 0);
    }

    // ---- 8 couplings on 1024-wide h ----
    for (int s = 0; s < 8; ++s) {
        const short* Wf = m1wf + (size_t)s * 512 * 512;
        const float* bf = m1_bf + (size_t)s * 512;
        const short* Wg = m1wg + (size_t)s * 512 * 512;
        const float* bg = m1_bg + (size_t)s * 512;
        dim3 g(512 / 64, ROWS / 128);
        mgemm<1, true, true><<<g, 256, 0, stream>>>(
            h + 512, 1024, 512, nullptr, 0, 0, Wf, 512, bf, 0, h, 1024, h, 1024);
        mgemm<1, true, true><<<g, 256, 0, stream>>>(
            h, 1024, 512, nullptr, 0, 0, Wg, 512, bg, 0, h + 512, 1024, h + 512, 1024);
    }

    // ---- lin2 ----
    {
        dim3 g(512 / 64, ROWS / 128);
        mgemm<1, true, false><<<g, 256, 0, stream>>>(
            pe, 32, 32, h, 1024, 1024, w2, 1056, lin2_b, 0, rb, 512, nullptr, 0);
    }

    // ---- 8 couplings on 512-wide r ----
    for (int s = 0; s < 8; ++s) {
        const short* Wf = m2wf + (size_t)s * 256 * 256;
        const float* bf = m2_bf + (size_t)s * 256;
        const short* Wg = m2wg + (size_t)s * 256 * 256;
        const float* bg = m2_bg + (size_t)s * 256;
        dim3 g(256 / 64, ROWS / 128);
        mgemm<1, true, true><<<g, 256, 0, stream>>>(
            rb + 256, 512, 256, nullptr, 0, 0, Wf, 256, bf, 0, rb, 512, rb, 512);
        mgemm<1, true, true><<<g, 256, 0, stream>>>(
            rb, 512, 256, nullptr, 0, 0, Wg, 256, bg, 0, rb + 256, 512, rb + 256, 512);
    }

    out_kernel<<<(ROWS * 64) / 256, 256, 0, stream>>>(rb, out_W, out_b, out);
}

// Round 13
// 1545.810 us; speedup vs baseline: 2.7329x; 1.5646x over previous
//
#include <hip/hip_runtime.h>
#include <math.h>

// DecoderCenter — Round 13 (resubmit of R11/R12 — infra timeouts): chain-GEMM v2 with
// workspace repacked to R7's proven 217.15 MB footprint.
// rb overlays dead fp32-h; hb in rb's old slot; conv scratch overlays hb slot;
// feat/base1 in peb-slot tail. Total = 54,287,984 floats.

#define LRELU(v) ((v) >= 0.0f ? (v) : 0.01f * (v))

static constexpr int BATCH = 4;
static constexpr int NPTS  = 8192;
static constexpr int ROWS  = BATCH * NPTS;   // 32768

typedef short bf16x8 __attribute__((ext_vector_type(8)));
typedef float f32x4  __attribute__((ext_vector_type(4)));

static __device__ __forceinline__ short f2bf(float f) {
    unsigned u = __float_as_uint(f);
    unsigned r = (u + 0x7fffu + ((u >> 16) & 1u)) >> 16;
    return (short)r;
}
static __device__ __forceinline__ unsigned split2u(float v) {
    unsigned hi = (unsigned)(unsigned short)f2bf(v);
    float hf = __uint_as_float(hi << 16);
    unsigned lo = (unsigned)(unsigned short)f2bf(v - hf);
    return hi | (lo << 16);
}

// ---------------- im2col (unchanged R7) ----------------
__global__ void im2col_kernel(const float* __restrict__ in, float* __restrict__ col,
                              int Cin, int Hi, int Wi, int Ho, int Wo,
                              int pad, int CinG, int K, int G) {
    int idx = blockIdx.x * blockDim.x + threadIdx.x;
    int total = G * 256 * K;
    if (idx >= total) return;
    int k = idx % K; int t = idx / K;
    int row = t & 255; int g = t >> 8;
    int b = row >> 6, hw = row & 63;
    int oh = hw / Wo, ow = hw - oh * Wo;
    int ic = k / 9, r9 = k - ic * 9;
    int kh = r9 / 3, kw = r9 - kh * 3;
    int ih = oh + kh - pad, iw = ow + kw - pad;
    float v = 0.f;
    if (hw < Ho * Wo && (unsigned)ih < (unsigned)Hi && (unsigned)iw < (unsigned)Wi)
        v = in[((long)(b * Cin + g * CinG + ic) * Hi + ih) * Wi + iw];
    col[idx] = v;
}

// ---------------- split-K conv GEMM (unchanged R7, passing) ----------------
__global__ __launch_bounds__(256) void conv_mgemm_splitk(
    const float* __restrict__ A, const float* __restrict__ W, int K, int Kc,
    float* __restrict__ partial, int Cout, int OG)
{
    __shared__ short Ah[128 * 32], Alo[128 * 32];
    __shared__ short Bh[64 * 32],  Blo[64 * 32];
    const int r0 = blockIdx.y * 128, c0 = blockIdx.x * 64;
    const int s = blockIdx.z;
    const int k0 = s * Kc;
    const int k1 = min(k0 + Kc, K);
    const float* Ag = A + (size_t)(c0 / OG) * 256 * K;
    const int tid = threadIdx.x;
    const int lane = tid & 63, w = tid >> 6;
    const int wr = (w >> 1) * 64, wc = (w & 1) * 32;
    const int l16 = lane & 15, lg = lane >> 4;

    f32x4 acc[4][2] = {};
    const int sar = tid >> 1, sak = (tid & 1) * 16;
    const int sbc = tid >> 2, sbk = tid & 3;

    for (int kt = k0; kt < k1; kt += 32) {
        __syncthreads();
        {
            const float* ap = Ag + (size_t)(r0 + sar) * K + kt + sak;
            bf16x8 h0, h1, L0, L1;
            unsigned p;
            #define SPL(vec, dst_h, dst_l, i0) \
                p = split2u(vec.x); dst_h[i0+0] = (short)p; dst_l[i0+0] = (short)(p >> 16); \
                p = split2u(vec.y); dst_h[i0+1] = (short)p; dst_l[i0+1] = (short)(p >> 16); \
                p = split2u(vec.z); dst_h[i0+2] = (short)p; dst_l[i0+2] = (short)(p >> 16); \
                p = split2u(vec.w); dst_h[i0+3] = (short)p; dst_l[i0+3] = (short)(p >> 16);
            {
                float4 va = *(const float4*)(ap + 0);
                float4 vb = *(const float4*)(ap + 4);
                SPL(va, h0, L0, 0) SPL(vb, h0, L0, 4)
            }
            {
                float4 va = *(const float4*)(ap + 8);
                float4 vb = *(const float4*)(ap + 12);
                SPL(va, h1, L1, 0) SPL(vb, h1, L1, 4)
            }
            int base = ((sar >> 4) * 4 + (sak >> 3)) * 128 + (sar & 15) * 8;
            *(bf16x8*)&Ah[base]        = h0; *(bf16x8*)&Ah[base + 128]  = h1;
            *(bf16x8*)&Alo[base]       = L0; *(bf16x8*)&Alo[base + 128] = L1;
        }
        {
            const float* bp = W + (size_t)(c0 + sbc) * K + kt + sbk * 8;
            float4 va = *(const float4*)(bp);
            float4 vb = *(const float4*)(bp + 4);
            bf16x8 hh, ll;
            unsigned p;
            SPL(va, hh, ll, 0) SPL(vb, hh, ll, 4)
            #undef SPL
            int base = ((sbc >> 4) * 4 + sbk) * 128 + (sbc & 15) * 8;
            *(bf16x8*)&Bh[base] = hh; *(bf16x8*)&Blo[base] = ll;
        }
        __syncthreads();
        bf16x8 ah[4], al[4], bh[2], bl[2];
        #pragma unroll
        for (int m = 0; m < 4; ++m) {
            int o = ((wr >> 4) + m) * 512 + lg * 128 + l16 * 8;
            ah[m] = *(const bf16x8*)&Ah[o];
            al[m] = *(const bf16x8*)&Alo[o];
        }
        #pragma unroll
        for (int n = 0; n < 2; ++n) {
            int o = ((wc >> 4) + n) * 512 + lg * 128 + l16 * 8;
            bh[n] = *(const bf16x8*)&Bh[o];
            bl[n] = *(const bf16x8*)&Blo[o];
        }
        #pragma unroll
        for (int m = 0; m < 4; ++m)
            #pragma unroll
            for (int n = 0; n < 2; ++n) {
                acc[m][n] = __builtin_amdgcn_mfma_f32_16x16x32_bf16(ah[m], bh[n], acc[m][n], 0, 0, 0);
                acc[m][n] = __builtin_amdgcn_mfma_f32_16x16x32_bf16(al[m], bh[n], acc[m][n], 0, 0, 0);
                acc[m][n] = __builtin_amdgcn_mfma_f32_16x16x32_bf16(ah[m], bl[n], acc[m][n], 0, 0, 0);
            }
    }

    float* pp = partial + (size_t)s * 256 * Cout;
    #pragma unroll
    for (int m = 0; m < 4; ++m) {
        int rbase = r0 + wr + m * 16 + lg * 4;
        #pragma unroll
        for (int n = 0; n < 2; ++n) {
            int c = c0 + wc + n * 16 + l16;
            #pragma unroll
            for (int j = 0; j < 4; ++j)
                pp[(size_t)(rbase + j) * Cout + c] = acc[m][n][j];
        }
    }
}

__global__ void conv_reduce_kernel(const float* __restrict__ partial,
                                   const float* __restrict__ bias, float* __restrict__ C,
                                   int S, int Cout, int HWo) {
    int c = blockIdx.x * 256 + threadIdx.x;
    if (c >= Cout) return;
    int r = blockIdx.y;
    int b = r >> 6, hw = r & 63;
    if (hw >= HWo) return;
    float acc = bias[c];
    for (int s = 0; s < S; ++s)
        acc += partial[((size_t)s * 256 + r) * Cout + c];
    C[((size_t)b * Cout + c) * HWo + hw] = LRELU(acc);
}

// ---------------- positional encoding -> bf16 directly ----------------
__global__ void pe_kernel(const float* __restrict__ points, short* __restrict__ peb, int total) {
    int idx = blockIdx.x * blockDim.x + threadIdx.x;
    if (idx >= total) return;
    int j = idx & 31;
    int r = idx >> 5;
    int oct = j >> 1, c = j & 1;
    float f = exp2f(0.5f * (float)oct);
    peb[idx] = f2bf(sinf(points[r * 2 + c] * f));
}

// ---------------- base1 ----------------
__global__ void base1_kernel(const float* __restrict__ feat, const float* __restrict__ W,
                             const float* __restrict__ b, float* __restrict__ base) {
    int wid = (int)((blockIdx.x * blockDim.x + threadIdx.x) >> 6);
    int lane = threadIdx.x & 63;
    if (wid >= BATCH * 1024) return;
    int bb = wid >> 10, oc = wid & 1023;
    const float* fr = feat + bb * 2048;
    const float* wr = W + (long)oc * 2080 + 32;
    float acc = 0.f;
    for (int k = lane; k < 2048; k += 64) acc += fr[k] * wr[k];
    #pragma unroll
    for (int off = 32; off; off >>= 1) acc += __shfl_down(acc, off);
    if (lane == 0) base[wid] = acc + b[oc];
}

// ---------------- weight conversions ----------------
__global__ void cvt_bf16_kernel(const float* __restrict__ in, short* __restrict__ out, int n4) {
    int i = blockIdx.x * blockDim.x + threadIdx.x;
    if (i >= n4) return;
    float4 v = *(const float4*)(in + (size_t)i * 4);
    short4 s;
    s.x = f2bf(v.x); s.y = f2bf(v.y); s.z = f2bf(v.z); s.w = f2bf(v.w);
    *(short4*)(out + (size_t)i * 4) = s;
}

__global__ void cvt_w1pe_kernel(const float* __restrict__ W, short* __restrict__ out) {
    int i = blockIdx.x * blockDim.x + threadIdx.x;
    if (i >= 1024 * 32) return;
    int r = i >> 5, c = i & 31;
    out[i] = f2bf(W[(size_t)r * 2080 + c]);
}

// ---------------- chain GEMM v2: BM=128, BN=256, BK=32, 8 waves ----------------
template<int BIAS_MODE, bool LEAKY, bool RESID, bool A1BF, bool SHADOW>
__global__ __launch_bounds__(512) void mgemm2(
    const void* __restrict__ A1v, int lda1, int K1,
    const short* __restrict__ A2, int lda2, int K2,
    const short* __restrict__ W, int ldw,
    const float* __restrict__ bias, int ldbias,
    float* __restrict__ C, int ldc, short* __restrict__ Cb,
    const float* __restrict__ resid, int ldres)
{
    __shared__ short Al[128 * 32];   // 8 KB
    __shared__ short Bl[256 * 32];   // 16 KB
    const int r0 = blockIdx.y * 128, c0 = blockIdx.x * 256;
    const int tid = threadIdx.x;
    const int lane = tid & 63, w = tid >> 6;
    const int wr = (w >> 2) * 64, wc = (w & 3) * 64;
    const int l16 = lane & 15, lg = lane >> 4;

    f32x4 acc[4][4] = {};

    const int arow = tid >> 2, akg = tid & 3;        // A: 128 rows x 4 kgroups
    const int bcol = tid >> 1, bkg0 = (tid & 1) * 2; // B: 256 cols x 2 kgroups/thread

    for (int src = 0; src < 2; ++src) {
        const int K   = src ? K2 : K1;
        if (K == 0) continue;
        const int lda = src ? lda2 : lda1;
        const int kb  = src ? K1 : 0;
        for (int kt = 0; kt < K; kt += 32) {
            __syncthreads();
            {   // stage A
                bf16x8 s;
                if (src == 0 && !A1BF) {
                    const float* ap = (const float*)A1v + (size_t)(r0 + arow) * lda + kt + akg * 8;
                    float4 v0 = *(const float4*)(ap + 0);
                    float4 v1 = *(const float4*)(ap + 4);
                    s[0] = f2bf(v0.x); s[1] = f2bf(v0.y); s[2] = f2bf(v0.z); s[3] = f2bf(v0.w);
                    s[4] = f2bf(v1.x); s[5] = f2bf(v1.y); s[6] = f2bf(v1.z); s[7] = f2bf(v1.w);
                } else {
                    const short* ap = (src ? A2 : (const short*)A1v) + (size_t)(r0 + arow) * lda + kt + akg * 8;
                    s = *(const bf16x8*)ap;
                }
                *(bf16x8*)&Al[((arow >> 4) * 4 + akg) * 128 + (arow & 15) * 8] = s;
            }
            {   // stage B
                const short* bp = W + (size_t)(c0 + bcol) * ldw + kb + kt + bkg0 * 8;
                bf16x8 b0 = *(const bf16x8*)bp;
                bf16x8 b1 = *(const bf16x8*)(bp + 8);
                int base = ((bcol >> 4) * 4 + bkg0) * 128 + (bcol & 15) * 8;
                *(bf16x8*)&Bl[base]       = b0;
                *(bf16x8*)&Bl[base + 128] = b1;
            }
            __syncthreads();
            bf16x8 af[4], bfr[4];
            #pragma unroll
            for (int m = 0; m < 4; ++m)
                af[m] = *(const bf16x8*)&Al[((wr >> 4) + m) * 512 + lg * 128 + l16 * 8];
            #pragma unroll
            for (int n = 0; n < 4; ++n)
                bfr[n] = *(const bf16x8*)&Bl[((wc >> 4) + n) * 512 + lg * 128 + l16 * 8];
            #pragma unroll
            for (int m = 0; m < 4; ++m)
                #pragma unroll
                for (int n = 0; n < 4; ++n)
                    acc[m][n] = __builtin_amdgcn_mfma_f32_16x16x32_bf16(af[m], bfr[n], acc[m][n], 0, 0, 0);
        }
    }

    #pragma unroll
    for (int m = 0; m < 4; ++m) {
        int rbase = r0 + wr + m * 16 + lg * 4;
        #pragma unroll
        for (int n = 0; n < 4; ++n) {
            int c = c0 + wc + n * 16 + l16;
            #pragma unroll
            for (int j = 0; j < 4; ++j) {
                int r = rbase + j;
                float v = acc[m][n][j];
                if (BIAS_MODE == 1) v += bias[c];
                else if (BIAS_MODE == 2) v += bias[(r >> 13) * ldbias + c];
                if (LEAKY) v = LRELU(v);
                if (RESID) v += resid[(size_t)r * ldres + c];
                C[(size_t)r * ldc + c] = v;
                if (SHADOW) Cb[(size_t)r * ldc + c] = f2bf(v);
            }
        }
    }
}

// ---------------- final head ----------------
__global__ void out_kernel(const float* __restrict__ rbuf, const float* __restrict__ outW,
                           const float* __restrict__ outb, float* __restrict__ out) {
    int wid = (int)((blockIdx.x * blockDim.x + threadIdx.x) >> 6);
    int lane = threadIdx.x & 63;
    if (wid >= ROWS) return;
    const float* rr = rbuf + (long)wid * 512;
    float a0 = 0.f, a1 = 0.f, a2 = 0.f;
    for (int k = lane; k < 512; k += 64) {
        float x = rr[k];
        a0 += x * outW[k];
        a1 += x * outW[512 + k];
        a2 += x * outW[1024 + k];
    }
    #pragma unroll
    for (int off = 32; off; off >>= 1) {
        a0 += __shfl_down(a0, off);
        a1 += __shfl_down(a1, off);
        a2 += __shfl_down(a2, off);
    }
    if (lane == 0) {
        int b = wid >> 13, n = wid & 8191;
        float* ob = out + (long)b * 3 * 8192 + n;
        ob[0]        = 1.1f / (1.f + expf(-(a0 + outb[0]))) - 0.05f;
        ob[8192]     = 1.1f / (1.f + expf(-(a1 + outb[1]))) - 0.05f;
        ob[2 * 8192] = 1.1f / (1.f + expf(-(a2 + outb[2]))) - 0.05f;
    }
}

extern "C" void kernel_launch(void* const* d_in, const int* in_sizes, int n_in,
                              void* d_out, int out_size, void* d_ws, size_t ws_size,
                              hipStream_t stream) {
    const float* feature = (const float*)d_in[0];
    const float* points  = (const float*)d_in[1];
    const float* cw1 = (const float*)d_in[2];  const float* cb1 = (const float*)d_in[3];
    const float* cw2 = (const float*)d_in[4];  const float* cb2 = (const float*)d_in[5];
    const float* cw3 = (const float*)d_in[6];  const float* cb3 = (const float*)d_in[7];
    const float* cw4 = (const float*)d_in[8];  const float* cb4 = (const float*)d_in[9];
    const float* cw5 = (const float*)d_in[10]; const float* cb5 = (const float*)d_in[11];
    const float* lin1_W = (const float*)d_in[12]; const float* lin1_b = (const float*)d_in[13];
    const float* m1_Wf = (const float*)d_in[14]; const float* m1_bf = (const float*)d_in[15];
    const float* m1_Wg = (const float*)d_in[16]; const float* m1_bg = (const float*)d_in[17];
    const float* lin2_W = (const float*)d_in[18]; const float* lin2_b = (const float*)d_in[19];
    const float* m2_Wf = (const float*)d_in[20]; const float* m2_bf = (const float*)d_in[21];
    const float* m2_Wg = (const float*)d_in[22]; const float* m2_bg = (const float*)d_in[23];
    const float* out_W = (const float*)d_in[24]; const float* out_b = (const float*)d_in[25];
    float* out = (float*)d_out;

    // ---- workspace repack (total 54,287,984 floats = R7's proven footprint) ----
    // [0 .. 0.52M)      peb (bf16 32768x32)
    // [0.52M .. 0.54M)  feat (8192 f) + base1 (4096 f)   <- peb-slot tail, never clobbered
    // [1.05M .. 34.60M) h fp32 (live lin1..m1 end); rb fp32 OVERLAYS from lin2 on (h dead)
    // [34.60M.. 51.38M) hb bf16 (live lin1..lin2); conv scratch overlays BEFORE lin1
    // [51.38M.. 54.29M) bf16 weights
    float* ws = (float*)d_ws;
    short* peb  = (short*)ws;                     // 32768*32 shorts = 0.5M f
    float* feat  = ws + 524288;                   // 8192 f
    float* base1 = ws + 532480;                   // 4096 f (ends 536,576 < 1,048,576)
    float* h  = ws + 1048576;                     // fp32 32768x1024
    float* rb = ws + 1048576;                     // fp32 32768x512, overlays dead h
    short* hb = (short*)(ws + 34603008);          // bf16 32768x1024
    // conv scratch overlays the hb slot (dead before lin1):
    float* xA      = ws + 34603008;               // 196,608 f
    float* xB      = ws + 34807808;               // 196,608 f
    float* colb    = ws + 35103008;               // im2col <= 4.13M f
    float* partial = ws + 39303008;               // split-K partials <= 3.15M f (ends ~42.5M)
    short* wsb  = (short*)(ws + 51380224);
    short* w1pe = wsb;                            // 1024*32
    short* w2   = w1pe + 1024 * 32;               // 512*1056
    short* m1wf = w2 + 512 * 1056;                // 8*512*512
    short* m1wg = m1wf + (size_t)8 * 512 * 512;
    short* m2wf = m1wg + (size_t)8 * 512 * 512;   // 8*256*256
    short* m2wg = m2wf + (size_t)8 * 256 * 256;   // ends at float-offset 54,287,984

    // ---- chain weight conversions ----
    {
        int n;
        n = 8 * 512 * 512 / 4;
        cvt_bf16_kernel<<<(n + 255) / 256, 256, 0, stream>>>(m1_Wf, m1wf, n);
        cvt_bf16_kernel<<<(n + 255) / 256, 256, 0, stream>>>(m1_Wg, m1wg, n);
        n = 8 * 256 * 256 / 4;
        cvt_bf16_kernel<<<(n + 255) / 256, 256, 0, stream>>>(m2_Wf, m2wf, n);
        cvt_bf16_kernel<<<(n + 255) / 256, 256, 0, stream>>>(m2_Wg, m2wg, n);
        n = 512 * 1056 / 4;
        cvt_bf16_kernel<<<(n + 255) / 256, 256, 0, stream>>>(lin2_W, w2, n);
        cvt_w1pe_kernel<<<(1024 * 32 + 255) / 256, 256, 0, stream>>>(lin1_W, w1pe);
    }

    // ---- conv stack (unchanged R7) ----
    auto layer = [&](const float* in, const float* wt, const float* bias, float* outp,
                     int Cin, int Hi, int Wi, int Ho, int Wo, int pad, int G, int Cout) {
        int CinG = Cin / G, K = CinG * 9, OG = Cout / G;
        int total = G * 256 * K;
        im2col_kernel<<<(total + 255) / 256, 256, 0, stream>>>(
            in, colb, Cin, Hi, Wi, Ho, Wo, pad, CinG, K, G);
        int steps = K / 32;
        int S = (steps + 7) / 8;
        int Kc = ((steps + S - 1) / S) * 32;
        dim3 g(Cout / 64, 2, S);
        conv_mgemm_splitk<<<g, 256, 0, stream>>>(colb, wt, K, Kc, partial, Cout, OG);
        dim3 gr((Cout + 255) / 256, 256);
        conv_reduce_kernel<<<gr, 256, 0, stream>>>(partial, bias, outp, S, Cout, Ho * Wo);
    };
    layer(feature, cw1, cb1, xA, 1792, 8, 8, 8, 8, 1, 4, 768);
    layer(xA, cw2, cb2, xB, 768, 8, 8, 8, 8, 1, 3, 768);
    layer(xB, cw3, cb3, xA, 768, 8, 8, 8, 8, 1, 2, 768);
    layer(xA, cw4, cb4, xB, 768, 8, 8, 6, 6, 0, 3, 768);
    layer(xB, cw5, cb5, feat, 768, 6, 6, 4, 4, 0, 1, 128);

    base1_kernel<<<(BATCH * 1024 * 64) / 256, 256, 0, stream>>>(feat, lin1_W, lin1_b, base1);
    pe_kernel<<<(ROWS * 32) / 256, 256, 0, stream>>>(points, peb, ROWS * 32);

    // ---- lin1: h(+hb) = leaky(peb @ w1pe.T + base1[batch]) ----
    {
        dim3 g(1024 / 256, ROWS / 128);
        mgemm2<2, true, false, true, true><<<g, 512, 0, stream>>>(
            peb, 32, 32, nullptr, 0, 0, w1pe, 32, base1, 1024, h, 1024, hb, nullptr, 0);
    }

    // ---- 8 couplings on 1024-wide h (A from hb shadow, resid from fp32 h) ----
    for (int s = 0; s < 8; ++s) {
        const short* Wf = m1wf + (size_t)s * 512 * 512;
        const float* bf = m1_bf + (size_t)s * 512;
        const short* Wg = m1wg + (size_t)s * 512 * 512;
        const float* bg = m1_bg + (size_t)s * 512;
        dim3 g(512 / 256, ROWS / 128);
        mgemm2<1, true, true, true, true><<<g, 512, 0, stream>>>(
            hb + 512, 1024, 512, nullptr, 0, 0, Wf, 512, bf, 0, h, 1024, hb, h, 1024);
        mgemm2<1, true, true, true, true><<<g, 512, 0, stream>>>(
            hb, 1024, 512, nullptr, 0, 0, Wg, 512, bg, 0, h + 512, 1024, hb + 512, h + 512, 1024);
    }

    // ---- lin2: rb = leaky([peb, hb] @ w2.T + lin2_b)  (rb overlays dead fp32 h) ----
    {
        dim3 g(512 / 256, ROWS / 128);
        mgemm2<1, true, false, true, false><<<g, 512, 0, stream>>>(
            peb, 32, 32, hb, 1024, 1024, w2, 1056, lin2_b, 0, rb, 512, nullptr, nullptr, 0);
    }

    // ---- 8 couplings on 512-wide rb (fp32 A staging, single col block) ----
    for (int s = 0; s < 8; ++s) {
        const short* Wf = m2wf + (size_t)s * 256 * 256;
        const float* bf = m2_bf + (size_t)s * 256;
        const short* Wg = m2wg + (size_t)s * 256 * 256;
        const float* bg = m2_bg + (size_t)s * 256;
        dim3 g(256 / 256, ROWS / 128);
        mgemm2<1, true, true, false, false><<<g, 512, 0, stream>>>(
            rb + 256, 512, 256, nullptr, 0, 0, Wf, 256, bf, 0, rb, 512, nullptr, rb, 512);
        mgemm2<1, true, true, false, false><<<g, 512, 0, stream>>>(
            rb, 512, 256, nullptr, 0, 0, Wg, 256, bg, 0, rb + 256, 512, nullptr, rb + 256, 512);
    }

    out_kernel<<<(ROWS * 64) / 256, 256, 0, stream>>>(rb, out_W, out_b, out);
}